// Round 2
// baseline (2683.773 us; speedup 1.0000x reference)
//
#include <hip/hip_runtime.h>
#include <hip/hip_bf16.h>

typedef __bf16 bf16x8 __attribute__((ext_vector_type(8)));
typedef __bf16 bf16x4 __attribute__((ext_vector_type(4)));
typedef float  f32x4  __attribute__((ext_vector_type(4)));
typedef float  f32x16 __attribute__((ext_vector_type(16)));
typedef int    i32x4  __attribute__((ext_vector_type(4)));

// Problem dims
#define NB 64
#define NT 512
#define ND 512
#define NH 1024
#define NG 4096  // 4H

// workspace layout (bytes) — total 314,052,608
#define OFF_BAR 0u          // 4 groups x 256 per-wave tags (4B) = 4 KB
#define OFF_H   4096u       // h double buffer: 2 x 64 x 1024 bf16 = 256 KB
#define OFF_EB  266240u     // E as bf16: 32000x512
#define OFF_WT  33034240u   // W^T bf16: 4096x512
#define OFF_UT  37228544u   // U^T bf16: 4096x1024
#define OFF_XW  45617152u   // xw bf16: (T,B,4096) = 256 MB

__device__ __forceinline__ void gl_lds16(const void* g, void* l) {
  typedef const unsigned __attribute__((address_space(1)))* gp_t;
  typedef unsigned __attribute__((address_space(3)))* lp_t;
  __builtin_amdgcn_global_load_lds((gp_t)g, (lp_t)l, 16, 0, 0);
}

__device__ __forceinline__ float sigf(float x) {
  return 1.0f / (1.0f + __expf(-x));
}

// 8 coherent (LLC) 16B loads from consecutive 64B offsets + drain.
// Outputs EARLY-CLOBBER: must not alias the address pair.
__device__ __forceinline__ void load_h_frags(unsigned long long a, i32x4* A) {
  asm volatile(
      "global_load_dwordx4 %0, %[a], off sc0 sc1\n\t"
      "global_load_dwordx4 %1, %[a], off offset:64 sc0 sc1\n\t"
      "global_load_dwordx4 %2, %[a], off offset:128 sc0 sc1\n\t"
      "global_load_dwordx4 %3, %[a], off offset:192 sc0 sc1\n\t"
      "global_load_dwordx4 %4, %[a], off offset:256 sc0 sc1\n\t"
      "global_load_dwordx4 %5, %[a], off offset:320 sc0 sc1\n\t"
      "global_load_dwordx4 %6, %[a], off offset:384 sc0 sc1\n\t"
      "global_load_dwordx4 %7, %[a], off offset:448 sc0 sc1\n\t"
      "s_waitcnt vmcnt(0)"
      : "=&v"(A[0]), "=&v"(A[1]), "=&v"(A[2]), "=&v"(A[3]),
        "=&v"(A[4]), "=&v"(A[5]), "=&v"(A[6]), "=&v"(A[7])
      : [a] "v"(a)
      : "memory");
}

// ---------------- prep kernels ----------------
__global__ void k_zero(uint4* p, int n) {
  int i = blockIdx.x * blockDim.x + threadIdx.x;
  int stride = gridDim.x * blockDim.x;
  uint4 z; z.x = 0; z.y = 0; z.z = 0; z.w = 0;
  for (; i < n; i += stride) p[i] = z;
}

__global__ void k_cvt(const float* __restrict__ in, __bf16* __restrict__ out, int n4) {
  int i = blockIdx.x * blockDim.x + threadIdx.x;
  int stride = gridDim.x * blockDim.x;
  for (; i < n4; i += stride) {
    float4 f = ((const float4*)in)[i];
    bf16x4 o;
    o.x = (__bf16)f.x; o.y = (__bf16)f.y; o.z = (__bf16)f.z; o.w = (__bf16)f.w;
    ((bf16x4*)out)[i] = o;
  }
}

// out[c][r] = (bf16) in[r][c];  in is (R,C) f32, out is (C,R) bf16
__global__ void k_transpose(const float* __restrict__ in, __bf16* __restrict__ out,
                            int R, int C) {
  __shared__ __bf16 tile[64][72];
  int c0 = blockIdx.x * 64, r0 = blockIdx.y * 64;
  for (int i = threadIdx.x; i < 4096; i += 256) {
    int r = i >> 6, c = i & 63;
    tile[r][c] = (__bf16)in[(size_t)(r0 + r) * C + c0 + c];
  }
  __syncthreads();
  for (int i = threadIdx.x; i < 4096; i += 256) {
    int c = i >> 6, r = i & 63;
    out[(size_t)(c0 + c) * R + r0 + r] = tile[r][c];
  }
}

// ---------------- GEMM1: xw[t][b][g] = E[ids[bt]] @ W + b ----------------
__global__ __launch_bounds__(256, 2) void k_gemm_xw(
    const int* __restrict__ ids, const __bf16* __restrict__ Ebf,
    const __bf16* __restrict__ Wt, const float* __restrict__ bias,
    __bf16* __restrict__ xw) {
  __shared__ __align__(16) char smem[32768];  // A tile 16K + B tile 16K
  char* ldsA = smem;
  char* ldsB = smem + 16384;

  const int tid = threadIdx.x;
  const int lane = tid & 63, w = tid >> 6;
  const int bm = blockIdx.x >> 5;          // 0..255
  const int bn0 = (blockIdx.x & 31) * 128; // col base

  const int l8r = lane >> 3, pc = lane & 7;
  size_t asrc[4], bsrc[4];
#pragma unroll
  for (int is = 0; is < 4; ++is) {
    int row = w * 32 + is * 8 + l8r;
    int id = ids[bm * 128 + row];
    asrc[is] = (size_t)id * ND + (size_t)(((pc ^ (row & 7)) * 8));
    int gn = bn0 + row;
    bsrc[is] = (size_t)gn * ND + (size_t)(((pc ^ (row & 7)) * 8));
  }

  const int rm = (w & 1) * 64, cn = (w >> 1) * 64;
  const int l31 = lane & 31, l5 = lane >> 5;
  f32x16 acc[2][2] = {};

  for (int kk = 0; kk < 8; ++kk) {
#pragma unroll
    for (int is = 0; is < 4; ++is) {
      gl_lds16(Ebf + asrc[is] + kk * 64, ldsA + w * 4096 + is * 1024);
      gl_lds16(Wt + bsrc[is] + kk * 64, ldsB + w * 4096 + is * 1024);
    }
    __syncthreads();
#pragma unroll
    for (int ksub = 0; ksub < 4; ++ksub) {
      int c = ksub * 2 + l5;
      bf16x8 af[2], bfr[2];
#pragma unroll
      for (int mt = 0; mt < 2; ++mt) {
        int row = rm + mt * 32 + l31;
        af[mt] = *(const bf16x8*)(ldsA + row * 128 + ((c ^ (row & 7)) << 4));
      }
#pragma unroll
      for (int nt = 0; nt < 2; ++nt) {
        int rowb = cn + nt * 32 + l31;
        bfr[nt] = *(const bf16x8*)(ldsB + rowb * 128 + ((c ^ (rowb & 7)) << 4));
      }
#pragma unroll
      for (int mt = 0; mt < 2; ++mt)
#pragma unroll
        for (int nt = 0; nt < 2; ++nt)
          acc[mt][nt] = __builtin_amdgcn_mfma_f32_32x32x16_bf16(
              af[mt], bfr[nt], acc[mt][nt], 0, 0, 0);
    }
    __syncthreads();
  }

#pragma unroll
  for (int nt = 0; nt < 2; ++nt) {
    int g = bn0 + cn + nt * 32 + l31;
    float bv = bias[g];
#pragma unroll
    for (int mt = 0; mt < 2; ++mt) {
#pragma unroll
      for (int r = 0; r < 16; ++r) {
        int row = (r & 3) + 8 * (r >> 2) + 4 * l5;
        int bt = bm * 128 + rm + mt * 32 + row;
        int tt = bt & 511, bb = bt >> 9;
        xw[(size_t)(tt * 64 + bb) * NG + g] = (__bf16)(acc[mt][nt][r] + bv);
      }
    }
  }
}

// ---------------- persistent LSTM scan ----------------
// 256 blocks x 256 thr. block: ms=bid&3 -> batches [ms*16,+16); nj=bid>>2 -> j in [nj*16,+16)
// wave w K-splits [w*256,+256). U slice held REGISTER-RESIDENT (32 x bf16x8 per wave).
//
// Sync: per-wave tag dwords (no atomics). Tag[ms][nj*4+w] = number of steps
// completed by that wave, stored sc0 sc1 after the wave's own h write-through drain.
// Consumer wave w only depends on h cols [w*256,+256) = blocks nj in [16w,16w+16),
// so it polls exactly those 64 tags (one dword per lane, 64-lane load + __all).
// zp (LDS) reuse across steps is guarded by the end-of-step __syncthreads.
__global__ __launch_bounds__(256, 1) void k_lstm(
    const int* __restrict__ ids, const __bf16* __restrict__ xw,
    const __bf16* __restrict__ Ut, float* __restrict__ out,
    __bf16* __restrict__ hbuf, unsigned* __restrict__ bar) {
  extern __shared__ char dynlds[];
  char* ubuf = dynlds;                       // 131072 B: U fragments (init staging only)
  float* zp = (float*)(dynlds + 131072);     // 16384 B: [wv][q][16b][16j]

  const int tid = threadIdx.x;
  const int lane = tid & 63, w = tid >> 6;
  const int bid = blockIdx.x;
  const int ms = bid & 3, nj = bid >> 2;
  const int b0 = ms * 16, j0 = nj * 16;

  const int bn = lane & 15;  // n (j-local) for B frags / MFMA
  const int kc = lane >> 4;  // k-chunk 0..3

  // stage U fragments into LDS once, in exact fragment order:
  // frag (w,q,ks) for lane L sits at ((w*4+q)*8+ks)*1024 + L*16.
#pragma unroll
  for (int q = 0; q < 4; ++q) {
#pragma unroll
    for (int ks = 0; ks < 8; ++ks) {
      const __bf16* src =
          Ut + (size_t)(q * NH + j0 + bn) * NH + w * 256 + ks * 32 + kc * 8;
      gl_lds16(src, ubuf + (((w * 4 + q) * 8 + ks) << 10));
    }
  }
  __syncthreads();

  // hoist all 32 B-fragments into registers (1 wave/SIMD -> VGPRs are free)
  bf16x8 Bf[8][4];
#pragma unroll
  for (int ks = 0; ks < 8; ++ks)
#pragma unroll
    for (int q = 0; q < 4; ++q)
      Bf[ks][q] =
          *(const bf16x8*)(ubuf + ((((w * 4 + q) * 8 + ks) << 6) + lane) * 16);

  const int eb = tid >> 4, ej = tid & 15;
  const int bg = b0 + eb, jg = j0 + ej;
  float c_st = 0.0f, h_st = 0.0f;

  const int am = lane & 15;  // batch row for A frags
  const unsigned long long hbase =
      (unsigned long long)(hbuf) + ((b0 + am) * NH + w * 256 + kc * 8) * 2ull;
  const unsigned long long hwaddr0 =
      (unsigned long long)(hbuf) + (bg * NH + jg) * 2ull;
  // poll: wave w needs tags [ms*256 + w*64, +64) -> lane L reads one dword
  const unsigned long long pollW =
      (unsigned long long)(bar) +
      (unsigned long long)(ms * 1024 + w * 256 + (lane << 2));
  // this wave's own tag
  const unsigned long long tagA =
      (unsigned long long)(bar) +
      (unsigned long long)(ms * 1024 + ((nj * 4 + w) << 2));

  // pipeline prologue: xw/ids for t=0
  const __bf16* xwp0 = xw + ((size_t)(0 * 64 + bg) << 12) + jg;
  __bf16 xr0 = xwp0[0], xr1 = xwp0[NH], xr2 = xwp0[2 * NH], xr3 = xwp0[3 * NH];
  int idv = ids[bg * NT + 0];

#pragma unroll 1
  for (int t = 0; t < NT; ++t) {
    // 1. spin until the 16 producer blocks of our column range finished step t-1.
    //    vmcnt is clean here: previous iteration force-drained everything.
    {
      bool ok;
      do {
        int v;
        asm volatile(
            "global_load_dword %0, %[a], off sc0 sc1\n\t"
            "s_waitcnt vmcnt(0)"
            : "=&v"(v) : [a] "v"(pollW) : "memory");
        ok = __all(v >= t);
      } while (!ok);
    }

    // 2. h_t fragments straight from LLC
    i32x4 Ar[8];
    load_h_frags(hbase + (unsigned long long)((t & 1) * (NB * NH * 2)), Ar);

    // 3. prefetch xw/ids for t+1 (issued here, force-drained by step-t h-store
    //    drain below, consumed next iteration -> HBM latency fully hidden)
    const int tp = (t + 1) & (NT - 1);
    const __bf16* xwn = xw + ((size_t)(tp * 64 + bg) << 12) + jg;
    __bf16 nx0 = xwn[0], nx1 = xwn[NH], nx2 = xwn[2 * NH], nx3 = xwn[3 * NH];
    int nid = ids[bg * NT + tp];

    // 4. MFMA: z partials, B-fragments from registers
    f32x4 acc[4] = {{0, 0, 0, 0}, {0, 0, 0, 0}, {0, 0, 0, 0}, {0, 0, 0, 0}};
#pragma unroll
    for (int ks = 0; ks < 8; ++ks) {
      bf16x8 a = __builtin_bit_cast(bf16x8, Ar[ks]);
#pragma unroll
      for (int q = 0; q < 4; ++q)
        acc[q] = __builtin_amdgcn_mfma_f32_16x16x32_bf16(a, Bf[ks][q], acc[q], 0, 0, 0);
    }

    // 5. partials to LDS: C layout col=lane&15 (=j), row=kc*4+r (=b)
#pragma unroll
    for (int q = 0; q < 4; ++q)
#pragma unroll
      for (int r = 0; r < 4; ++r)
        zp[((w * 4 + q) << 8) + ((kc * 4 + r) << 4) + bn] = acc[q][r];
    __syncthreads();

    float z0 = 0, z1 = 0, z2 = 0, z3 = 0;
#pragma unroll
    for (int wv = 0; wv < 4; ++wv) {
      z0 += zp[((wv * 4 + 0) << 8) + (eb << 4) + ej];
      z1 += zp[((wv * 4 + 1) << 8) + (eb << 4) + ej];
      z2 += zp[((wv * 4 + 2) << 8) + (eb << 4) + ej];
      z3 += zp[((wv * 4 + 3) << 8) + (eb << 4) + ej];
    }
    z0 += (float)xr0; z1 += (float)xr1; z2 += (float)xr2; z3 += (float)xr3;
    float iv = sigf(z0), fv = sigf(z1), gv = sigf(z2), ov = sigf(z3);
    float cn = fv * c_st + iv * gv;
    float hn = ov * sigf(cn);
    bool m = (idv != 0);
    c_st = m ? cn : c_st;
    h_st = m ? hn : h_st;

    // outs (f32, normal cached store — never read back by us)
    out[(size_t)bg * (NT * NH) + (size_t)t * NH + jg] = h_st;

    // h_{t+1} write-through to LLC, then drain THIS wave's stores
    // (also completes the xw/ids prefetch + out store)
    {
      unsigned hv = (unsigned)__builtin_bit_cast(unsigned short, (__bf16)h_st);
      unsigned long long ha =
          hwaddr0 + (unsigned long long)(((t + 1) & 1) * (NB * NH * 2));
      asm volatile(
          "global_store_short %[a], %[d], off sc0 sc1\n\t"
          "s_waitcnt vmcnt(0)"
          :: [a] "v"(ha), [d] "v"(hv) : "memory");
    }

    // 6. per-wave tag: this wave's h for step t is in LLC
    if (lane == 0) {
      unsigned tv = (unsigned)(t + 1);
      asm volatile(
          "global_store_dword %[a], %[d], off sc0 sc1"
          :: [a] "v"(tagA), [d] "v"(tv) : "memory");
    }
    __syncthreads();  // guards zp reuse (next step's writes vs this step's reads)

    // rotate pipeline registers
    xr0 = nx0; xr1 = nx1; xr2 = nx2; xr3 = nx3; idv = nid;
  }

  // final h, c
  out[33554432u + bg * NH + jg] = h_st;
  out[33554432u + 65536u + bg * NH + jg] = c_st;
}

// ---------------- launch ----------------
extern "C" void kernel_launch(void* const* d_in, const int* in_sizes, int n_in,
                              void* d_out, int out_size, void* d_ws, size_t ws_size,
                              hipStream_t stream) {
  const int* ids = (const int*)d_in[0];
  const float* E = (const float*)d_in[1];
  const float* W = (const float*)d_in[2];
  const float* U = (const float*)d_in[3];
  const float* bias = (const float*)d_in[4];
  char* ws = (char*)d_ws;
  __bf16* Ebf = (__bf16*)(ws + OFF_EB);
  __bf16* Wt = (__bf16*)(ws + OFF_WT);
  __bf16* Ut = (__bf16*)(ws + OFF_UT);
  __bf16* xw = (__bf16*)(ws + OFF_XW);
  __bf16* hbuf = (__bf16*)(ws + OFF_H);
  unsigned* bar = (unsigned*)(ws + OFF_BAR);
  float* out = (float*)d_out;

  // allow 144 KB dynamic LDS for k_lstm (idempotent; safe under graph capture)
  (void)hipFuncSetAttribute((const void*)k_lstm,
                            hipFuncAttributeMaxDynamicSharedMemorySize, 147456);

  // zero barrier + h buffers (266240 bytes)
  hipLaunchKernelGGL(k_zero, dim3(65), dim3(256), 0, stream, (uint4*)ws, 16640);
  // E -> bf16
  hipLaunchKernelGGL(k_cvt, dim3(2048), dim3(256), 0, stream, E, Ebf, 4096000);
  // W^T, U^T -> bf16
  hipLaunchKernelGGL(k_transpose, dim3(64, 8), dim3(256), 0, stream, W, Wt, 512, 4096);
  hipLaunchKernelGGL(k_transpose, dim3(64, 16), dim3(256), 0, stream, U, Ut, 1024, 4096);
  // xw = gather(E)@W + b
  hipLaunchKernelGGL(k_gemm_xw, dim3(8192), dim3(256), 0, stream, ids, Ebf, Wt, bias, xw);
  // persistent LSTM scan
  hipLaunchKernelGGL(k_lstm, dim3(256), dim3(256), 147456, stream, ids, xw, Ut, out, hbuf, bar);
}

// Round 3
// 1772.572 us; speedup vs baseline: 1.5141x; 1.5141x over previous
//
#include <hip/hip_runtime.h>
#include <hip/hip_bf16.h>

typedef __bf16 bf16x8 __attribute__((ext_vector_type(8)));
typedef __bf16 bf16x4 __attribute__((ext_vector_type(4)));
typedef float  f32x4  __attribute__((ext_vector_type(4)));
typedef float  f32x16 __attribute__((ext_vector_type(16)));
typedef int    i32x4  __attribute__((ext_vector_type(4)));

// Problem dims
#define NB 64
#define NT 512
#define ND 512
#define NH 1024
#define NG 4096  // 4H

// workspace layout (bytes) — total 314,052,608 (unchanged envelope)
// h triple buffer: buf0 @ OFF_H, buf1 @ OFF_H+128K, buf2 @ OFF_H+256K
// buf2 ALIASES the first 128KB of Ebf — Ebf is dead after k_gemm_xw, and
// buf2's sentinel-fill is launched after the GEMM.
#define OFF_H   4096u       // 3 x 64 x 1024 bf16 = 3 x 128 KB
#define OFF_EB  266240u     // E as bf16: 32000x512 (32 MB)
#define OFF_WT  33034240u   // W^T bf16: 4096x512
#define OFF_UT  37228544u   // U^T bf16: 4096x1024
#define OFF_XW  45617152u   // xw bf16: (T,B,4096) = 256 MB

#define HBUF_STRIDE 131072u // one h buffer: 64*1024*2

__device__ __forceinline__ void gl_lds16(const void* g, void* l) {
  typedef const unsigned __attribute__((address_space(1)))* gp_t;
  typedef unsigned __attribute__((address_space(3)))* lp_t;
  __builtin_amdgcn_global_load_lds((gp_t)g, (lp_t)l, 16, 0, 0);
}

__device__ __forceinline__ float sigf(float x) {
  return 1.0f / (1.0f + __expf(-x));
}

// 8 coherent (LLC) 16B loads from consecutive 64B offsets + drain.
// Outputs EARLY-CLOBBER: must not alias the address pair.
__device__ __forceinline__ void load_h_frags(unsigned long long a, i32x4* A) {
  asm volatile(
      "global_load_dwordx4 %0, %[a], off sc0 sc1\n\t"
      "global_load_dwordx4 %1, %[a], off offset:64 sc0 sc1\n\t"
      "global_load_dwordx4 %2, %[a], off offset:128 sc0 sc1\n\t"
      "global_load_dwordx4 %3, %[a], off offset:192 sc0 sc1\n\t"
      "global_load_dwordx4 %4, %[a], off offset:256 sc0 sc1\n\t"
      "global_load_dwordx4 %5, %[a], off offset:320 sc0 sc1\n\t"
      "global_load_dwordx4 %6, %[a], off offset:384 sc0 sc1\n\t"
      "global_load_dwordx4 %7, %[a], off offset:448 sc0 sc1\n\t"
      "s_waitcnt vmcnt(0)"
      : "=&v"(A[0]), "=&v"(A[1]), "=&v"(A[2]), "=&v"(A[3]),
        "=&v"(A[4]), "=&v"(A[5]), "=&v"(A[6]), "=&v"(A[7])
      : [a] "v"(a)
      : "memory");
}

// ---------------- prep kernels ----------------
__global__ void k_zero(uint4* p, int n) {
  int i = blockIdx.x * blockDim.x + threadIdx.x;
  int stride = gridDim.x * blockDim.x;
  uint4 z; z.x = 0; z.y = 0; z.z = 0; z.w = 0;
  for (; i < n; i += stride) p[i] = z;
}

__global__ void k_fill(uint4* p, int n) {
  int i = blockIdx.x * blockDim.x + threadIdx.x;
  int stride = gridDim.x * blockDim.x;
  uint4 s; s.x = 0xFFFFFFFFu; s.y = 0xFFFFFFFFu; s.z = 0xFFFFFFFFu; s.w = 0xFFFFFFFFu;
  for (; i < n; i += stride) p[i] = s;
}

__global__ void k_cvt(const float* __restrict__ in, __bf16* __restrict__ out, int n4) {
  int i = blockIdx.x * blockDim.x + threadIdx.x;
  int stride = gridDim.x * blockDim.x;
  for (; i < n4; i += stride) {
    float4 f = ((const float4*)in)[i];
    bf16x4 o;
    o.x = (__bf16)f.x; o.y = (__bf16)f.y; o.z = (__bf16)f.z; o.w = (__bf16)f.w;
    ((bf16x4*)out)[i] = o;
  }
}

// out[c][r] = (bf16) in[r][c];  in is (R,C) f32, out is (C,R) bf16
__global__ void k_transpose(const float* __restrict__ in, __bf16* __restrict__ out,
                            int R, int C) {
  __shared__ __bf16 tile[64][72];
  int c0 = blockIdx.x * 64, r0 = blockIdx.y * 64;
  for (int i = threadIdx.x; i < 4096; i += 256) {
    int r = i >> 6, c = i & 63;
    tile[r][c] = (__bf16)in[(size_t)(r0 + r) * C + c0 + c];
  }
  __syncthreads();
  for (int i = threadIdx.x; i < 4096; i += 256) {
    int c = i >> 6, r = i & 63;
    out[(size_t)(c0 + c) * R + r0 + r] = tile[r][c];
  }
}

// ---------------- GEMM1: xw[t][b][g] = E[ids[bt]] @ W + b ----------------
__global__ __launch_bounds__(256, 2) void k_gemm_xw(
    const int* __restrict__ ids, const __bf16* __restrict__ Ebf,
    const __bf16* __restrict__ Wt, const float* __restrict__ bias,
    __bf16* __restrict__ xw) {
  __shared__ __align__(16) char smem[32768];  // A tile 16K + B tile 16K
  char* ldsA = smem;
  char* ldsB = smem + 16384;

  const int tid = threadIdx.x;
  const int lane = tid & 63, w = tid >> 6;
  const int bm = blockIdx.x >> 5;          // 0..255
  const int bn0 = (blockIdx.x & 31) * 128; // col base

  const int l8r = lane >> 3, pc = lane & 7;
  size_t asrc[4], bsrc[4];
#pragma unroll
  for (int is = 0; is < 4; ++is) {
    int row = w * 32 + is * 8 + l8r;
    int id = ids[bm * 128 + row];
    asrc[is] = (size_t)id * ND + (size_t)(((pc ^ (row & 7)) * 8));
    int gn = bn0 + row;
    bsrc[is] = (size_t)gn * ND + (size_t)(((pc ^ (row & 7)) * 8));
  }

  const int rm = (w & 1) * 64, cn = (w >> 1) * 64;
  const int l31 = lane & 31, l5 = lane >> 5;
  f32x16 acc[2][2] = {};

  for (int kk = 0; kk < 8; ++kk) {
#pragma unroll
    for (int is = 0; is < 4; ++is) {
      gl_lds16(Ebf + asrc[is] + kk * 64, ldsA + w * 4096 + is * 1024);
      gl_lds16(Wt + bsrc[is] + kk * 64, ldsB + w * 4096 + is * 1024);
    }
    __syncthreads();
#pragma unroll
    for (int ksub = 0; ksub < 4; ++ksub) {
      int c = ksub * 2 + l5;
      bf16x8 af[2], bfr[2];
#pragma unroll
      for (int mt = 0; mt < 2; ++mt) {
        int row = rm + mt * 32 + l31;
        af[mt] = *(const bf16x8*)(ldsA + row * 128 + ((c ^ (row & 7)) << 4));
      }
#pragma unroll
      for (int nt = 0; nt < 2; ++nt) {
        int rowb = cn + nt * 32 + l31;
        bfr[nt] = *(const bf16x8*)(ldsB + rowb * 128 + ((c ^ (rowb & 7)) << 4));
      }
#pragma unroll
      for (int mt = 0; mt < 2; ++mt)
#pragma unroll
        for (int nt = 0; nt < 2; ++nt)
          acc[mt][nt] = __builtin_amdgcn_mfma_f32_32x32x16_bf16(
              af[mt], bfr[nt], acc[mt][nt], 0, 0, 0);
    }
    __syncthreads();
  }

#pragma unroll
  for (int nt = 0; nt < 2; ++nt) {
    int g = bn0 + cn + nt * 32 + l31;
    float bv = bias[g];
#pragma unroll
    for (int mt = 0; mt < 2; ++mt) {
#pragma unroll
      for (int r = 0; r < 16; ++r) {
        int row = (r & 3) + 8 * (r >> 2) + 4 * l5;
        int bt = bm * 128 + rm + mt * 32 + row;
        int tt = bt & 511, bb = bt >> 9;
        xw[(size_t)(tt * 64 + bb) * NG + g] = (__bf16)(acc[mt][nt][r] + bv);
      }
    }
  }
}

// ---------------- persistent LSTM scan ----------------
// 256 blocks x 256 thr. block: ms=bid&3 -> batches [ms*16,+16); nj=bid>>2 -> j in [nj*16,+16)
// wave w K-splits [w*256,+256). U fragments REGISTER-RESIDENT (staged through a
// 32KB LDS window so no full-U LDS copy exists -> compiler cannot re-read it).
//
// Sync protocol (NO tags, NO atomics): valid h is always in [0,1) (h = o*sig(c),
// both factors in (0,1); masked h holds its previous value >= 0), so the bf16
// sign bit of every valid h element is 0. Sentinel 0xFFFF is unreachable.
// Consumers poll the h DATA: a slice is ready iff no sign bit is set.
// Triple buffer R(t)=buf[t%3], W(t)=buf[(t+1)%3], F(t)=buf[(t+2)%3]:
//  - after the block-wide zp barrier (== all 4 waves verified all 64 producer
//    tiles of step t => every block finished reading h_t), each thread
//    sentinel-fills its own element in F(t);
//  - vmcnt(0) drains the fill, THEN h_{t+1} is stored to W(t).
// Fill-before-release ordering => a consumer that has verified all h_{t+1}
// sees sentinel (never stale h_{t-1}) when it starts polling R(t+2)=F(t).
// out values staged in LDS, dumped every 32 steps => HBM write-ack off the
// per-step serial path.
__global__ __launch_bounds__(256, 1) void k_lstm(
    const int* __restrict__ ids, const __bf16* __restrict__ xw,
    const __bf16* __restrict__ Ut, float* __restrict__ out,
    __bf16* __restrict__ hb) {
  extern __shared__ char dynlds[];
  float* ost = (float*)dynlds;               // 32 KB: U staging window, then out stage [32][256]
  float* zp  = (float*)(dynlds + 32768);     // 17408 B: skewed z partials

  const int tid = threadIdx.x;
  const int lane = tid & 63, w = tid >> 6;
  const int bid = blockIdx.x;
  const int ms = bid & 3, nj = bid >> 2;
  const int b0 = ms * 16, j0 = nj * 16;

  const int bn = lane & 15;  // n (j-local) for B frags / MFMA
  const int kc = lane >> 4;  // k-chunk 0..3

  // ---- stage U fragments through a 32KB window, chunk per gate q ----
  // frag (w,ks) of chunk q sits at (w*8+ks)*1024 + lane*16 (gl_lds lane spread)
  bf16x8 Bf[8][4];
#pragma unroll
  for (int q = 0; q < 4; ++q) {
#pragma unroll
    for (int ks = 0; ks < 8; ++ks) {
      const __bf16* src =
          Ut + (size_t)(q * NH + j0 + bn) * NH + w * 256 + ks * 32 + kc * 8;
      gl_lds16(src, (char*)dynlds + ((w * 8 + ks) << 10));
    }
    __syncthreads();
#pragma unroll
    for (int ks = 0; ks < 8; ++ks)
      Bf[ks][q] =
          *(const bf16x8*)((char*)dynlds + (((w * 8 + ks) << 6) + lane) * 16);
    __syncthreads();
  }

  const int eb = tid >> 4, ej = tid & 15;
  const int bg = b0 + eb, jg = j0 + ej;
  float c_st = 0.0f, h_st = 0.0f;

  const int am = lane & 15;  // batch row for A frags
  const unsigned long long hlane =
      (unsigned long long)(hb) + ((b0 + am) * NH + w * 256 + kc * 8) * 2ull;
  const unsigned long long hown =
      (unsigned long long)(hb) + (bg * NH + jg) * 2ull;

  unsigned offR = 0, offW = HBUF_STRIDE, offF = 2 * HBUF_STRIDE;

  // pipeline prologue: xw/ids for t=0
  const __bf16* xwp0 = xw + ((size_t)(0 * 64 + bg) << 12) + jg;
  __bf16 xr0 = xwp0[0], xr1 = xwp0[NH], xr2 = xwp0[2 * NH], xr3 = xwp0[3 * NH];
  int idv = ids[bg * NT + 0];

#pragma unroll 1
  for (int t = 0; t < NT; ++t) {
    const unsigned long long hbR = hlane + offR;

    // A) cheap probe: first fragment until all sign bits clear
    {
      bool ok;
      do {
        i32x4 v;
        asm volatile(
            "global_load_dwordx4 %0, %[a], off sc0 sc1\n\t"
            "s_waitcnt vmcnt(0)"
            : "=&v"(v) : [a] "v"(hbR) : "memory");
        unsigned b = (unsigned)(v[0] | v[1] | v[2] | v[3]) & 0x80008000u;
        ok = __all((int)(b == 0));
      } while (!ok);
    }

    // B) full slice load + full sentinel check (stores may land out of order)
    i32x4 Ar[8];
    for (;;) {
      load_h_frags(hbR, Ar);
      unsigned bad = 0;
#pragma unroll
      for (int i = 0; i < 8; ++i)
        bad |= (unsigned)(Ar[i][0] | Ar[i][1] | Ar[i][2] | Ar[i][3]);
      bad &= 0x80008000u;
      if (__all((int)(bad == 0))) break;
    }

    // C) prefetch xw/ids for t+1 (plain loads; drained by the pre-release vmcnt(0))
    const int tp = (t + 1) & (NT - 1);
    const __bf16* xwn = xw + ((size_t)(tp * 64 + bg) << 12) + jg;
    __bf16 nx0 = xwn[0], nx1 = xwn[NH], nx2 = xwn[2 * NH], nx3 = xwn[3 * NH];
    int nid = ids[bg * NT + tp];

    // D) MFMA: z partials, B-fragments from registers
    f32x4 acc[4] = {{0, 0, 0, 0}, {0, 0, 0, 0}, {0, 0, 0, 0}, {0, 0, 0, 0}};
#pragma unroll
    for (int ks = 0; ks < 8; ++ks) {
      bf16x8 a = __builtin_bit_cast(bf16x8, Ar[ks]);
#pragma unroll
      for (int q = 0; q < 4; ++q)
        acc[q] = __builtin_amdgcn_mfma_f32_16x16x32_bf16(a, Bf[ks][q], acc[q], 0, 0, 0);
    }

    // E) partials to LDS (skewed stride 17 to break 4-way bank conflicts)
#pragma unroll
    for (int q = 0; q < 4; ++q)
#pragma unroll
      for (int r = 0; r < 4; ++r)
        zp[(w * 4 + q) * 272 + (kc * 4 + r) * 17 + bn] = acc[q][r];
    __syncthreads();  // BLOCK GATE: all 4 waves verified all producer tiles

    // F) sentinel-fill own element of F(t) — safe only after the gate
    {
      unsigned sv = 0xFFFFu;
      unsigned long long fa = hown + offF;
      asm volatile(
          "global_store_short %[a], %[d], off sc0 sc1"
          :: [a] "v"(fa), [d] "v"(sv) : "memory");
    }

    // G) reduce + gates
    float z0 = 0, z1 = 0, z2 = 0, z3 = 0;
#pragma unroll
    for (int wv = 0; wv < 4; ++wv) {
      z0 += zp[(wv * 4 + 0) * 272 + eb * 17 + ej];
      z1 += zp[(wv * 4 + 1) * 272 + eb * 17 + ej];
      z2 += zp[(wv * 4 + 2) * 272 + eb * 17 + ej];
      z3 += zp[(wv * 4 + 3) * 272 + eb * 17 + ej];
    }
    z0 += (float)xr0; z1 += (float)xr1; z2 += (float)xr2; z3 += (float)xr3;
    float iv = sigf(z0), fv = sigf(z1), gv = sigf(z2), ov = sigf(z3);
    float cn = fv * c_st + iv * gv;
    float hn = ov * sigf(cn);
    bool m = (idv != 0);
    c_st = m ? cn : c_st;
    h_st = m ? hn : h_st;

    // H) stage out in LDS (flushed every 32 steps, off the serial path)
    ost[(t & 31) * 256 + tid] = h_st;

    // I) drain: sentinel fill (+ prefetches + any prior dump stores)
    asm volatile("s_waitcnt vmcnt(0)" ::: "memory");

    // J) release: h_{t+1} to W(t) — the data itself is the ready flag
    {
      unsigned hv = (unsigned)__builtin_bit_cast(unsigned short, (__bf16)h_st);
      unsigned long long ha = hown + offW;
      asm volatile(
          "global_store_short %[a], %[d], off sc0 sc1"
          :: [a] "v"(ha), [d] "v"(hv) : "memory");
    }

    // K) periodic out dump (plain cached stores; acks drain next step)
    if ((t & 31) == 31) {
      float* ob = out + (size_t)bg * (NT * NH) + (size_t)(t - 31) * NH + jg;
#pragma unroll
      for (int s = 0; s < 32; ++s)
        ob[(size_t)s * NH] = ost[s * 256 + tid];
    }

    __syncthreads();  // zp + ost reuse guard

    // L) rotate buffers + pipeline registers
    unsigned tmp = offR; offR = offW; offW = offF; offF = tmp;
    xr0 = nx0; xr1 = nx1; xr2 = nx2; xr3 = nx3; idv = nid;
  }

  // final h, c
  out[33554432u + bg * NH + jg] = h_st;
  out[33554432u + 65536u + bg * NH + jg] = c_st;
}

// ---------------- launch ----------------
extern "C" void kernel_launch(void* const* d_in, const int* in_sizes, int n_in,
                              void* d_out, int out_size, void* d_ws, size_t ws_size,
                              hipStream_t stream) {
  const int* ids = (const int*)d_in[0];
  const float* E = (const float*)d_in[1];
  const float* W = (const float*)d_in[2];
  const float* U = (const float*)d_in[3];
  const float* bias = (const float*)d_in[4];
  char* ws = (char*)d_ws;
  __bf16* Ebf = (__bf16*)(ws + OFF_EB);
  __bf16* Wt = (__bf16*)(ws + OFF_WT);
  __bf16* Ut = (__bf16*)(ws + OFF_UT);
  __bf16* xw = (__bf16*)(ws + OFF_XW);
  __bf16* hb = (__bf16*)(ws + OFF_H);
  float* out = (float*)d_out;

  // allow 50176 B dynamic LDS for k_lstm (idempotent; safe under graph capture)
  (void)hipFuncSetAttribute((const void*)k_lstm,
                            hipFuncAttributeMaxDynamicSharedMemorySize, 50176);

  // h buffers: buf0 = h_0 = zeros; buf1 = sentinel
  hipLaunchKernelGGL(k_zero, dim3(32), dim3(256), 0, stream, (uint4*)(ws + OFF_H), 8192);
  hipLaunchKernelGGL(k_fill, dim3(32), dim3(256), 0, stream,
                     (uint4*)(ws + OFF_H + HBUF_STRIDE), 8192);
  // E -> bf16
  hipLaunchKernelGGL(k_cvt, dim3(2048), dim3(256), 0, stream, E, Ebf, 4096000);
  // W^T, U^T -> bf16
  hipLaunchKernelGGL(k_transpose, dim3(64, 8), dim3(256), 0, stream, W, Wt, 512, 4096);
  hipLaunchKernelGGL(k_transpose, dim3(64, 16), dim3(256), 0, stream, U, Ut, 1024, 4096);
  // xw = gather(E)@W + b
  hipLaunchKernelGGL(k_gemm_xw, dim3(8192), dim3(256), 0, stream, ids, Ebf, Wt, bias, xw);
  // buf2 = sentinel (aliases head of Ebf — must run AFTER the GEMM)
  hipLaunchKernelGGL(k_fill, dim3(32), dim3(256), 0, stream,
                     (uint4*)(ws + OFF_H + 2 * HBUF_STRIDE), 8192);
  // persistent LSTM scan
  hipLaunchKernelGGL(k_lstm, dim3(256), dim3(256), 50176, stream, ids, xw, Ut, out, hb);
}